// Round 2
// baseline (5653.872 us; speedup 1.0000x reference)
//
#include <hip/hip_runtime.h>
#include <math.h>

#define B_  256
#define T_  48
#define D_  89
#define H_  128
#define C_  64
#define NH_ 8
#define HD_ 8
#define N2T 96   // 2*T

// output layout (floats)
#define XIMP_OFF 0
#define LOSS_OFF 1093632
#define HID_OFF  1093633
#define Y_OFF    2666497
#define YS_OFF   2666753

typedef unsigned short ushort_t;
typedef unsigned int uint_t;

__device__ __forceinline__ float wave_sum64(float v) {
    v += __shfl_xor(v, 32);
    v += __shfl_xor(v, 16);
    v += __shfl_xor(v, 8);
    v += __shfl_xor(v, 4);
    v += __shfl_xor(v, 2);
    v += __shfl_xor(v, 1);
    return v;
}

__device__ __forceinline__ float bfl(ushort_t u) {
    return __uint_as_float(((uint_t)u) << 16);
}

// ---------------- prep: transpose weights (bf16 for scan, f32 for transformer)
__device__ __forceinline__ void tr_bf16(const float* __restrict__ s, ushort_t* __restrict__ d,
                                        int li, int R, int C, bool zd) {
    int r = li / C, c = li - r * C;
    float v = s[li];
    if (zd && r == c) v = 0.f;
    uint_t u = __float_as_uint(v);
    u = (u + 0x7fffu + ((u >> 16) & 1u)) >> 16;   // RNE to bf16
    d[c * R + r] = (ushort_t)u;
}
__device__ __forceinline__ void tr_f32(const float* __restrict__ s, float* __restrict__ d,
                                       int li, int R, int C) {
    int r = li / C, c = li - r * C;
    d[c * R + r] = s[li];
}

__global__ void k_prep(const float* W_dh, const float* W_hist, const float* W_feat,
                       const float* W_wc, const float* W_ih, const float* W_hh,
                       ushort_t* W_dhT, ushort_t* W_histT, ushort_t* W_featT,
                       ushort_t* W_wcT, ushort_t* W_ihT, ushort_t* W_hhT,
                       const float* W_wo, const float* W_inp, const float* ain_w,
                       const float* aout_w, const float* ff1_w, const float* ff2_w,
                       const float* W_op1,
                       float* W_woT, float* W_inpT, float* ain_T,
                       float* aout_T, float* ff1_T, float* ff2_T, float* op1_T) {
    int i = blockIdx.x * 256 + threadIdx.x;
    if (i < 11392)        tr_bf16(W_dh,   W_dhT,   i,          128, 89,  false);
    else if (i < 22784)   tr_bf16(W_hist, W_histT, i - 11392,  89, 128,  false);
    else if (i < 30705)   tr_bf16(W_feat, W_featT, i - 22784,  89,  89,  true);
    else if (i < 46547)   tr_bf16(W_wc,   W_wcT,   i - 30705,  89, 178,  false);
    else if (i < 114899)  tr_bf16(W_ih,   W_ihT,   i - 46547, 384, 178,  false);
    else if (i < 164051)  tr_bf16(W_hh,   W_hhT,   i - 114899,384, 128,  false);
    else if (i < 171972)  tr_f32(W_wo,   W_woT,  i - 164051,  89, 89);
    else if (i < 177668)  tr_f32(W_inp,  W_inpT, i - 171972,  64, 89);
    else if (i < 189956)  tr_f32(ain_w,  ain_T,  i - 177668, 192, 64);
    else if (i < 194052)  tr_f32(aout_w, aout_T, i - 189956,  64, 64);
    else if (i < 198148)  tr_f32(ff1_w,  ff1_T,  i - 194052,  64, 64);
    else if (i < 202244)  tr_f32(ff2_w,  ff2_T,  i - 198148,  64, 64);
    else if (i < 210436)  tr_f32(W_op1,  op1_T,  i - 202244, 128, 64);
}

// ---------------- Phase A: decay factor + time encoder + positional encoding
__global__ void k_phaseA(const float* __restrict__ last_obs,
                         const float* __restrict__ deltas,
                         const float* __restrict__ medians,
                         const float* __restrict__ W_woT, const float* __restrict__ b_wo,
                         const float* __restrict__ W_inpT, const float* __restrict__ b_inp,
                         float* __restrict__ data) {
    int bt = blockIdx.x;
    int b = bt / T_;
    int t = bt - b * T_;
    __shared__ float dd[D_], lo[D_], dec[D_];
    int tid = threadIdx.x;
    int base = (b * T_ + t) * D_;
    if (tid < D_) {
        float dv = deltas[base + tid] - medians[tid];
        dd[tid] = dv;
        lo[tid] = last_obs[base + tid];
    }
    __syncthreads();
    if (tid < D_) {
        float acc = b_wo[tid];
        for (int j = 0; j < D_; ++j) acc = fmaf(dd[j], W_woT[j * D_ + tid], acc);
        float dv = dd[tid];
        float s = (dv > 0.f) ? 1.f : ((dv < 0.f) ? -1.f : 0.f);
        dec[tid] = 0.5f * (1.f - tanhf(s * fabsf(acc)));
    }
    __syncthreads();
    int c = tid & 63;
    int half = tid >> 6;
    const float* src = half ? dec : lo;
    float acc = b_inp[c];
    for (int j = 0; j < D_; ++j) acc = fmaf(src[j], W_inpT[j * C_ + c], acc);
    int i = c >> 1;
    float div = __expf((float)i * -0.28782313662425574f);
    float ang = (float)t * div;
    float pe = (c & 1) ? cosf(ang) : sinf(ang);
    data[((b * N2T) + half * T_ + t) * C_ + c] = acc + pe;
}

// ---------------- qkv: one block per (s,n); 192 threads; writes [n][h][s][d] layout.
__global__ void k_qkv(const float* __restrict__ data,
                      const float* __restrict__ ain_T, const float* __restrict__ ain_b,
                      float* __restrict__ qb, float* __restrict__ kb, float* __restrict__ vb) {
    int bn = blockIdx.x;
    int s = bn / N2T;
    int n = bn - s * N2T;
    __shared__ float row[C_];
    int tid = threadIdx.x;
    if (tid < C_) row[tid] = data[bn * C_ + tid];
    __syncthreads();
    float acc = ain_b[tid];
    for (int j = 0; j < C_; ++j) acc = fmaf(row[j], ain_T[j * 192 + tid], acc);
    int part = tid >> 6;
    int c = tid & 63;
    int h = c >> 3, d = c & 7;
    float* dst = (part == 0) ? qb : ((part == 1) ? kb : vb);
    dst[(((n * NH_ + h) * B_ + s) * HD_) + d] = acc;
}

// ---------------- attention: one block per (n,h); 256 threads (thread = s over B).
__global__ void k_attn(const float* __restrict__ qb, const float* __restrict__ kb,
                       const float* __restrict__ vb, float* __restrict__ attnO) {
    int n = blockIdx.x >> 3;
    int h = blockIdx.x & 7;
    __shared__ float k_lds[B_][HD_ + 1];
    __shared__ float v_lds[B_][HD_ + 1];
    int s = threadIdx.x;
    const float scale = 0.35355339059327373f; // 1/sqrt(8)
    size_t base = ((size_t)blockIdx.x * B_ + s) * HD_;
    float q[HD_];
    #pragma unroll
    for (int d = 0; d < HD_; ++d) q[d] = qb[base + d] * scale;
    #pragma unroll
    for (int d = 0; d < HD_; ++d) { k_lds[s][d] = kb[base + d]; v_lds[s][d] = vb[base + d]; }
    __syncthreads();
    float m = -1e30f;
    for (int t = 0; t < B_; ++t) {
        float sc = 0.f;
        #pragma unroll
        for (int d = 0; d < HD_; ++d) sc = fmaf(q[d], k_lds[t][d], sc);
        m = fmaxf(m, sc);
    }
    float l = 0.f;
    float acc[HD_] = {0.f, 0.f, 0.f, 0.f, 0.f, 0.f, 0.f, 0.f};
    for (int t = 0; t < B_; ++t) {
        float sc = 0.f;
        #pragma unroll
        for (int d = 0; d < HD_; ++d) sc = fmaf(q[d], k_lds[t][d], sc);
        float p = __expf(sc - m);
        l += p;
        #pragma unroll
        for (int d = 0; d < HD_; ++d) acc[d] = fmaf(p, v_lds[t][d], acc[d]);
    }
    float inv = 1.f / l;
    float* op = attnO + ((size_t)s * N2T + n) * C_ + h * HD_;
    #pragma unroll
    for (int d = 0; d < HD_; ++d) op[d] = acc[d] * inv;
}

// ---------------- transformer post-attn (transposed weights, coalesced)
__global__ void k_transform(const float* __restrict__ data,
                            const float* __restrict__ attnO,
                            const float* __restrict__ aout_T, const float* __restrict__ aout_b,
                            const float* __restrict__ ln1_g, const float* __restrict__ ln1_b,
                            const float* __restrict__ ff1_T, const float* __restrict__ ff1_b,
                            const float* __restrict__ ff2_T, const float* __restrict__ ff2_b,
                            const float* __restrict__ ln2_g, const float* __restrict__ ln2_b,
                            const float* __restrict__ op1_T, const float* __restrict__ b_op1,
                            float* __restrict__ val) {
    int bn = blockIdx.x;
    __shared__ float orow[C_], x1s[C_], hbuf[C_], x2s[C_];
    int c = threadIdx.x;
    float d0 = data[bn * C_ + c];
    orow[c] = attnO[bn * C_ + c];
    __syncthreads();
    float acc = aout_b[c];
    for (int j = 0; j < C_; ++j) acc = fmaf(orow[j], aout_T[j * C_ + c], acc);
    float r = d0 + acc;
    float mean = wave_sum64(r) * (1.f / 64.f);
    float df = r - mean;
    float var = wave_sum64(df * df) * (1.f / 64.f);
    float x1 = df * rsqrtf(var + 1e-5f) * ln1_g[c] + ln1_b[c];
    x1s[c] = x1;
    __syncthreads();
    acc = ff1_b[c];
    for (int j = 0; j < C_; ++j) acc = fmaf(x1s[j], ff1_T[j * C_ + c], acc);
    float ge = 0.5f * acc * (1.f + erff(acc * 0.7071067811865475f));
    hbuf[c] = ge;
    __syncthreads();
    acc = ff2_b[c];
    for (int j = 0; j < C_; ++j) acc = fmaf(hbuf[j], ff2_T[j * C_ + c], acc);
    float r2 = x1 + acc;
    float mean2 = wave_sum64(r2) * (1.f / 64.f);
    float df2 = r2 - mean2;
    float var2 = wave_sum64(df2 * df2) * (1.f / 64.f);
    float x2 = df2 * rsqrtf(var2 + 1e-5f) * ln2_g[c] + ln2_b[c];
    x2s[c] = x2;
    __syncthreads();
    #pragma unroll
    for (int rep = 0; rep < 2; ++rep) {
        int k = c + rep * 64;
        float a2 = b_op1[k];
        for (int j = 0; j < C_; ++j) a2 = fmaf(x2s[j], op1_T[j * H_ + k], a2);
        val[(size_t)bn * H_ + k] = a2;
    }
}

// ---------------- h0 = conv1d over n (96 -> 1)
__global__ void k_reduce_h0(const float* __restrict__ val,
                            const float* __restrict__ W_op2, const float* __restrict__ b_op2,
                            float* __restrict__ h0) {
    int b = blockIdx.x;
    int h = threadIdx.x;
    float acc = b_op2[0];
    for (int n = 0; n < N2T; ++n)
        acc = fmaf(val[((size_t)b * N2T + n) * H_ + h], W_op2[n], acc);
    h0[b * H_ + h] = acc;
}

// ---------------- per-step mask denominator
__global__ void k_den(const float* __restrict__ mask, float* __restrict__ den) {
    int t = blockIdx.x;
    int tid = threadIdx.x;
    float s = 0.f;
    const int total = B_ * D_;
    for (int i = tid; i < total; i += 256) {
        int b = i / D_;
        int d = i - b * D_;
        s += mask[(b * T_ + t) * D_ + d];
    }
    s = wave_sum64(s);
    __shared__ float red[4];
    if ((tid & 63) == 0) red[tid >> 6] = s;
    __syncthreads();
    if (tid == 0) den[t] = red[0] + red[1] + red[2] + red[3];
}

// ---------------- recurrent scan: 1 block / batch element; 384 threads; bf16 W^T
__global__ __launch_bounds__(384)
void k_scan(const float* __restrict__ x, const float* __restrict__ mask,
            const float* __restrict__ deltas,
            const ushort_t* __restrict__ W_dhT, const float* __restrict__ b_dh,
            const float* __restrict__ W_dx, const float* __restrict__ b_dx,
            const ushort_t* __restrict__ W_histT, const float* __restrict__ b_hist,
            const ushort_t* __restrict__ W_featT, const float* __restrict__ b_feat,
            const ushort_t* __restrict__ W_wcT, const float* __restrict__ b_wc,
            const ushort_t* __restrict__ W_ihT, const ushort_t* __restrict__ W_hhT,
            const float* __restrict__ b_ih, const float* __restrict__ b_hh,
            const float* __restrict__ W_cls, const float* __restrict__ b_cls,
            const float* __restrict__ h0,
            float* __restrict__ out, float* __restrict__ num_part) {
    int b = blockIdx.x;
    int tid = threadIdx.x;
    __shared__ float h[H_];
    __shared__ float xt[D_], dt[D_], xh[D_], xr[D_], diffb[D_];
    __shared__ float cat_gi[178];   // [ximp(89) | mt(89)]
    __shared__ float cat_b[178];    // [gx(89)   | mt(89)]
    __shared__ float gi[384], gh[384];

    if (tid < H_) h[tid] = h0[b * H_ + tid];

    for (int t = 0; t < T_; ++t) {
        int base = (b * T_ + t) * D_;
        if (tid < D_) {
            xt[tid] = x[base + tid];
            float m = mask[base + tid];
            cat_gi[D_ + tid] = m;
            cat_b[D_ + tid] = m;
            dt[tid] = deltas[base + tid];
        }
        __syncthreads();
        // phase 1: gamma_h, decay h
        if (tid < H_) {
            const ushort_t* w = W_dhT + tid;
            float a0 = 0.f, a1 = 0.f, a2 = 0.f, a3 = 0.f;
            for (int j = 0; j < 88; j += 4) {
                a0 = fmaf(dt[j],     bfl(w[(j)     * H_]), a0);
                a1 = fmaf(dt[j + 1], bfl(w[(j + 1) * H_]), a1);
                a2 = fmaf(dt[j + 2], bfl(w[(j + 2) * H_]), a2);
                a3 = fmaf(dt[j + 3], bfl(w[(j + 3) * H_]), a3);
            }
            a0 = fmaf(dt[88], bfl(w[88 * H_]), a0);
            float acc = b_dh[tid] + ((a0 + a1) + (a2 + a3));
            h[tid] *= __expf(-fmaxf(acc, 0.f));
        }
        __syncthreads();
        // phase 2: x_h, x_r, gamma_x
        if (tid < D_) {
            const ushort_t* w = W_histT + tid;
            float a0 = 0.f, a1 = 0.f, a2 = 0.f, a3 = 0.f;
            for (int j = 0; j < 128; j += 4) {
                a0 = fmaf(h[j],     bfl(w[(j)     * D_]), a0);
                a1 = fmaf(h[j + 1], bfl(w[(j + 1) * D_]), a1);
                a2 = fmaf(h[j + 2], bfl(w[(j + 2) * D_]), a2);
                a3 = fmaf(h[j + 3], bfl(w[(j + 3) * D_]), a3);
            }
            float acc = b_hist[tid] + ((a0 + a1) + (a2 + a3));
            xh[tid] = acc;
            float m = cat_gi[D_ + tid];
            xr[tid] = m * xt[tid] + (1.f - m) * acc;
            cat_b[tid] = __expf(-fmaxf(dt[tid] * W_dx[tid * 90] + b_dx[tid], 0.f));
        }
        __syncthreads();
        // phase 3: xu, beta, x_comb, x_imp
        if (tid < D_) {
            const ushort_t* wf = W_featT + tid;
            float a0 = 0.f, a1 = 0.f, a2 = 0.f, a3 = 0.f;
            for (int j = 0; j < 88; j += 4) {
                a0 = fmaf(xr[j],     bfl(wf[(j)     * D_]), a0);
                a1 = fmaf(xr[j + 1], bfl(wf[(j + 1) * D_]), a1);
                a2 = fmaf(xr[j + 2], bfl(wf[(j + 2) * D_]), a2);
                a3 = fmaf(xr[j + 3], bfl(wf[(j + 3) * D_]), a3);
            }
            a0 = fmaf(xr[88], bfl(wf[88 * D_]), a0);
            float xu = b_feat[tid] + ((a0 + a1) + (a2 + a3));
            const ushort_t* wc = W_wcT + tid;
            float c0 = 0.f, c1 = 0.f, c2 = 0.f, c3 = 0.f;
            for (int j = 0; j < 176; j += 4) {
                c0 = fmaf(cat_b[j],     bfl(wc[(j)     * D_]), c0);
                c1 = fmaf(cat_b[j + 1], bfl(wc[(j + 1) * D_]), c1);
                c2 = fmaf(cat_b[j + 2], bfl(wc[(j + 2) * D_]), c2);
                c3 = fmaf(cat_b[j + 3], bfl(wc[(j + 3) * D_]), c3);
            }
            c0 = fmaf(cat_b[176], bfl(wc[176 * D_]), c0);
            c1 = fmaf(cat_b[177], bfl(wc[177 * D_]), c1);
            float beta = b_wc[tid] + ((c0 + c1) + (c2 + c3));
            float xc = beta * xu + (1.f - beta) * xh[tid];
            float m = cat_gi[D_ + tid];
            float xi = m * xt[tid] + (1.f - m) * xc;
            cat_gi[tid] = xi;
            out[XIMP_OFF + base + tid] = xi;
            diffb[tid] = fabsf(xt[tid] - xc) * m;
        }
        __syncthreads();
        // loss partial on wave 0
        if (tid < 64) {
            float s = diffb[tid];
            if (tid + 64 < D_) s += diffb[tid + 64];
            s = wave_sum64(s);
            if (tid == 0) num_part[t * B_ + b] = s;
        }
        // phase 4: gi (178-dot), gh (128-dot) — all 384 threads, one output each
        {
            const ushort_t* wi = W_ihT + tid;
            float a0 = 0.f, a1 = 0.f, a2 = 0.f, a3 = 0.f;
            for (int j = 0; j < 176; j += 4) {
                a0 = fmaf(cat_gi[j],     bfl(wi[(j)     * 384]), a0);
                a1 = fmaf(cat_gi[j + 1], bfl(wi[(j + 1) * 384]), a1);
                a2 = fmaf(cat_gi[j + 2], bfl(wi[(j + 2) * 384]), a2);
                a3 = fmaf(cat_gi[j + 3], bfl(wi[(j + 3) * 384]), a3);
            }
            a0 = fmaf(cat_gi[176], bfl(wi[176 * 384]), a0);
            a1 = fmaf(cat_gi[177], bfl(wi[177 * 384]), a1);
            float giv = b_ih[tid] + ((a0 + a1) + (a2 + a3));
            const ushort_t* wh = W_hhT + tid;
            float c0 = 0.f, c1 = 0.f, c2 = 0.f, c3 = 0.f;
            for (int j = 0; j < 128; j += 4) {
                c0 = fmaf(h[j],     bfl(wh[(j)     * 384]), c0);
                c1 = fmaf(h[j + 1], bfl(wh[(j + 1) * 384]), c1);
                c2 = fmaf(h[j + 2], bfl(wh[(j + 2) * 384]), c2);
                c3 = fmaf(h[j + 3], bfl(wh[(j + 3) * 384]), c3);
            }
            float ghv = b_hh[tid] + ((c0 + c1) + (c2 + c3));
            gi[tid] = giv;
            gh[tid] = ghv;
        }
        __syncthreads();
        // phase 5: GRU update
        if (tid < H_) {
            float r = 1.f / (1.f + __expf(-(gi[tid] + gh[tid])));
            float z = 1.f / (1.f + __expf(-(gi[H_ + tid] + gh[H_ + tid])));
            float g = tanhf(gi[2 * H_ + tid] + r * gh[2 * H_ + tid]);
            float hn = (1.f - z) * g + z * h[tid];
            h[tid] = hn;
            out[HID_OFF + (size_t)(b * T_ + t) * H_ + tid] = hn;
        }
        __syncthreads();
    }
    // classifier
    if (tid < 64) {
        float s = h[tid] * W_cls[tid] + h[tid + 64] * W_cls[tid + 64];
        s = wave_sum64(s);
        if (tid == 0) {
            float y = s + b_cls[0];
            out[Y_OFF + b] = y;
            out[YS_OFF + b] = 1.f / (1.f + __expf(-y));
        }
    }
}

// ---------------- final loss reduction
__global__ void k_loss(const float* __restrict__ num_part, const float* __restrict__ den,
                       float* __restrict__ out) {
    int tid = threadIdx.x;
    float v = 0.f;
    if (tid < T_) {
        float s = 0.f;
        const float* np_ = num_part + tid * B_;
        for (int b = 0; b < B_; ++b) s += np_[b];
        v = s / (den[tid] + 1e-5f);
    }
    v = wave_sum64(v);
    if (tid == 0) out[LOSS_OFF] = v;
}

extern "C" void kernel_launch(void* const* d_in, const int* in_sizes, int n_in,
                              void* d_out, int out_size, void* d_ws, size_t ws_size,
                              hipStream_t stream) {
    const float* x        = (const float*)d_in[0];
    const float* mask     = (const float*)d_in[1];
    const float* deltas   = (const float*)d_in[2];
    const float* last_obs = (const float*)d_in[3];
    const float* medians  = (const float*)d_in[4];
    const float* W_dh  = (const float*)d_in[5];
    const float* b_dh  = (const float*)d_in[6];
    const float* W_dx  = (const float*)d_in[7];
    const float* b_dx  = (const float*)d_in[8];
    const float* W_hist= (const float*)d_in[9];
    const float* b_hist= (const float*)d_in[10];
    const float* W_feat= (const float*)d_in[11];
    const float* b_feat= (const float*)d_in[12];
    const float* W_wc  = (const float*)d_in[13];
    const float* b_wc  = (const float*)d_in[14];
    const float* W_wo  = (const float*)d_in[15];
    const float* b_wo  = (const float*)d_in[16];
    const float* W_cls = (const float*)d_in[17];
    const float* b_cls = (const float*)d_in[18];
    const float* W_ih  = (const float*)d_in[19];
    const float* W_hh  = (const float*)d_in[20];
    const float* b_ih  = (const float*)d_in[21];
    const float* b_hh  = (const float*)d_in[22];
    const float* W_inp = (const float*)d_in[23];
    const float* b_inp = (const float*)d_in[24];
    const float* W_op1 = (const float*)d_in[25];
    const float* b_op1 = (const float*)d_in[26];
    const float* W_op2 = (const float*)d_in[27];
    const float* b_op2 = (const float*)d_in[28];
    const float* attn_in_w  = (const float*)d_in[29];
    const float* attn_in_b  = (const float*)d_in[30];
    const float* attn_out_w = (const float*)d_in[31];
    const float* attn_out_b = (const float*)d_in[32];
    const float* ln1_g = (const float*)d_in[33];
    const float* ln1_b = (const float*)d_in[34];
    const float* ln2_g = (const float*)d_in[35];
    const float* ln2_b = (const float*)d_in[36];
    const float* ff1_w = (const float*)d_in[37];
    const float* ff1_b = (const float*)d_in[38];
    const float* ff2_w = (const float*)d_in[39];
    const float* ff2_b = (const float*)d_in[40];

    float* out = (float*)d_out;
    float* ws = (float*)d_ws;

    float* data  = ws;                                  // 1,572,864
    float* qb    = data  + (size_t)B_ * N2T * C_;       // 1,572,864
    float* kb    = qb    + (size_t)N2T * NH_ * B_ * HD_;
    float* vb    = kb    + (size_t)N2T * NH_ * B_ * HD_;
    float* attnO = vb    + (size_t)N2T * NH_ * B_ * HD_;
    float* val   = attnO + (size_t)B_ * N2T * C_;       // 3,145,728
    float* h0    = val   + (size_t)B_ * N2T * H_;       // 32,768
    float* den   = h0    + (size_t)B_ * H_;             // 48
    float* nump  = den   + 64;                          // 12,288
    float* W_woT = nump  + T_ * B_;                     // f32 transposed region
    float* W_inpT= W_woT + 7921;
    float* ain_T = W_inpT + 5696;
    float* aout_T= ain_T + 12288;
    float* ff1_T = aout_T + 4096;
    float* ff2_T = ff1_T + 4096;
    float* op1_T = ff2_T + 4096;
    ushort_t* bfbase = (ushort_t*)(op1_T + 8192);       // bf16 transposed region
    ushort_t* W_dhT   = bfbase;
    ushort_t* W_histT = W_dhT   + 11392;
    ushort_t* W_featT = W_histT + 11392;
    ushort_t* W_wcT   = W_featT + 7921;
    ushort_t* W_ihT   = W_wcT   + 15842;
    ushort_t* W_hhT   = W_ihT   + 68352;

    k_prep<<<823, 256, 0, stream>>>(W_dh, W_hist, W_feat, W_wc, W_ih, W_hh,
                                    W_dhT, W_histT, W_featT, W_wcT, W_ihT, W_hhT,
                                    W_wo, W_inp, attn_in_w, attn_out_w, ff1_w, ff2_w, W_op1,
                                    W_woT, W_inpT, ain_T, aout_T, ff1_T, ff2_T, op1_T);
    k_phaseA<<<B_ * T_, 128, 0, stream>>>(last_obs, deltas, medians, W_woT, b_wo, W_inpT, b_inp, data);
    k_qkv<<<B_ * N2T, 192, 0, stream>>>(data, ain_T, attn_in_b, qb, kb, vb);
    k_attn<<<N2T * NH_, 256, 0, stream>>>(qb, kb, vb, attnO);
    k_transform<<<B_ * N2T, 64, 0, stream>>>(data, attnO, aout_T, attn_out_b,
                                             ln1_g, ln1_b, ff1_T, ff1_b, ff2_T, ff2_b,
                                             ln2_g, ln2_b, op1_T, b_op1, val);
    k_reduce_h0<<<B_, H_, 0, stream>>>(val, W_op2, b_op2, h0);
    k_den<<<T_, 256, 0, stream>>>(mask, den);
    k_scan<<<B_, 384, 0, stream>>>(x, mask, deltas,
                                   W_dhT, b_dh, W_dx, b_dx, W_histT, b_hist, W_featT, b_feat,
                                   W_wcT, b_wc, W_ihT, W_hhT, b_ih, b_hh, W_cls, b_cls,
                                   h0, out, nump);
    k_loss<<<1, 64, 0, stream>>>(nump, den, out);
}

// Round 3
// 1640.826 us; speedup vs baseline: 3.4457x; 3.4457x over previous
//
#include <hip/hip_runtime.h>
#include <math.h>

#define B_  256
#define T_  48
#define D_  89
#define H_  128
#define C_  64
#define NH_ 8
#define HD_ 8
#define N2T 96   // 2*T
#define NB  4    // batch elems per scan block
#define NBLK (B_ / NB)   // 64 scan blocks

// output layout (floats)
#define XIMP_OFF 0
#define LOSS_OFF 1093632
#define HID_OFF  1093633
#define Y_OFF    2666497
#define YS_OFF   2666753

__device__ __forceinline__ float wave_sum64(float v) {
    v += __shfl_xor(v, 32);
    v += __shfl_xor(v, 16);
    v += __shfl_xor(v, 8);
    v += __shfl_xor(v, 4);
    v += __shfl_xor(v, 2);
    v += __shfl_xor(v, 1);
    return v;
}

// ---------------- prep: f32 transposes for the transformer-phase kernels only
__device__ __forceinline__ void tr_f32(const float* __restrict__ s, float* __restrict__ d,
                                       int li, int R, int C) {
    int r = li / C, c = li - r * C;
    d[c * R + r] = s[li];
}

__global__ void k_prep(const float* W_wo, const float* W_inp, const float* ain_w,
                       const float* aout_w, const float* ff1_w, const float* ff2_w,
                       const float* W_op1,
                       float* W_woT, float* W_inpT, float* ain_T,
                       float* aout_T, float* ff1_T, float* ff2_T, float* op1_T) {
    int i = blockIdx.x * 256 + threadIdx.x;
    if (i < 7921)         tr_f32(W_wo,   W_woT,  i,          89, 89);
    else if (i < 13617)   tr_f32(W_inp,  W_inpT, i - 7921,   64, 89);
    else if (i < 25905)   tr_f32(ain_w,  ain_T,  i - 13617, 192, 64);
    else if (i < 30001)   tr_f32(aout_w, aout_T, i - 25905,  64, 64);
    else if (i < 34097)   tr_f32(ff1_w,  ff1_T,  i - 30001,  64, 64);
    else if (i < 38193)   tr_f32(ff2_w,  ff2_T,  i - 34097,  64, 64);
    else if (i < 46385)   tr_f32(W_op1,  op1_T,  i - 38193, 128, 64);
}

// ---------------- Phase A: decay factor + time encoder + positional encoding
__global__ void k_phaseA(const float* __restrict__ last_obs,
                         const float* __restrict__ deltas,
                         const float* __restrict__ medians,
                         const float* __restrict__ W_woT, const float* __restrict__ b_wo,
                         const float* __restrict__ W_inpT, const float* __restrict__ b_inp,
                         float* __restrict__ data) {
    int bt = blockIdx.x;
    int b = bt / T_;
    int t = bt - b * T_;
    __shared__ float dd[D_], lo[D_], dec[D_];
    int tid = threadIdx.x;
    int base = (b * T_ + t) * D_;
    if (tid < D_) {
        float dv = deltas[base + tid] - medians[tid];
        dd[tid] = dv;
        lo[tid] = last_obs[base + tid];
    }
    __syncthreads();
    if (tid < D_) {
        float acc = b_wo[tid];
        for (int j = 0; j < D_; ++j) acc = fmaf(dd[j], W_woT[j * D_ + tid], acc);
        float dv = dd[tid];
        float s = (dv > 0.f) ? 1.f : ((dv < 0.f) ? -1.f : 0.f);
        dec[tid] = 0.5f * (1.f - tanhf(s * fabsf(acc)));
    }
    __syncthreads();
    int c = tid & 63;
    int half = tid >> 6;
    const float* src = half ? dec : lo;
    float acc = b_inp[c];
    for (int j = 0; j < D_; ++j) acc = fmaf(src[j], W_inpT[j * C_ + c], acc);
    int i = c >> 1;
    float div = __expf((float)i * -0.28782313662425574f);
    float ang = (float)t * div;
    float pe = (c & 1) ? cosf(ang) : sinf(ang);
    data[((b * N2T) + half * T_ + t) * C_ + c] = acc + pe;
}

// ---------------- qkv: one block per (s,n); 192 threads; writes [n][h][s][d] layout.
__global__ void k_qkv(const float* __restrict__ data,
                      const float* __restrict__ ain_T, const float* __restrict__ ain_b,
                      float* __restrict__ qb, float* __restrict__ kb, float* __restrict__ vb) {
    int bn = blockIdx.x;
    int s = bn / N2T;
    int n = bn - s * N2T;
    __shared__ float row[C_];
    int tid = threadIdx.x;
    if (tid < C_) row[tid] = data[bn * C_ + tid];
    __syncthreads();
    float acc = ain_b[tid];
    for (int j = 0; j < C_; ++j) acc = fmaf(row[j], ain_T[j * 192 + tid], acc);
    int part = tid >> 6;
    int c = tid & 63;
    int h = c >> 3, d = c & 7;
    float* dst = (part == 0) ? qb : ((part == 1) ? kb : vb);
    dst[(((n * NH_ + h) * B_ + s) * HD_) + d] = acc;
}

// ---------------- attention: one block per (n,h); 256 threads (thread = s over B).
__global__ void k_attn(const float* __restrict__ qb, const float* __restrict__ kb,
                       const float* __restrict__ vb, float* __restrict__ attnO) {
    int n = blockIdx.x >> 3;
    int h = blockIdx.x & 7;
    __shared__ float k_lds[B_][HD_ + 1];
    __shared__ float v_lds[B_][HD_ + 1];
    int s = threadIdx.x;
    const float scale = 0.35355339059327373f; // 1/sqrt(8)
    size_t base = ((size_t)blockIdx.x * B_ + s) * HD_;
    float q[HD_];
    #pragma unroll
    for (int d = 0; d < HD_; ++d) q[d] = qb[base + d] * scale;
    #pragma unroll
    for (int d = 0; d < HD_; ++d) { k_lds[s][d] = kb[base + d]; v_lds[s][d] = vb[base + d]; }
    __syncthreads();
    float m = -1e30f;
    for (int t = 0; t < B_; ++t) {
        float sc = 0.f;
        #pragma unroll
        for (int d = 0; d < HD_; ++d) sc = fmaf(q[d], k_lds[t][d], sc);
        m = fmaxf(m, sc);
    }
    float l = 0.f;
    float acc[HD_] = {0.f, 0.f, 0.f, 0.f, 0.f, 0.f, 0.f, 0.f};
    for (int t = 0; t < B_; ++t) {
        float sc = 0.f;
        #pragma unroll
        for (int d = 0; d < HD_; ++d) sc = fmaf(q[d], k_lds[t][d], sc);
        float p = __expf(sc - m);
        l += p;
        #pragma unroll
        for (int d = 0; d < HD_; ++d) acc[d] = fmaf(p, v_lds[t][d], acc[d]);
    }
    float inv = 1.f / l;
    float* op = attnO + ((size_t)s * N2T + n) * C_ + h * HD_;
    #pragma unroll
    for (int d = 0; d < HD_; ++d) op[d] = acc[d] * inv;
}

// ---------------- transformer post-attn (transposed weights, coalesced)
__global__ void k_transform(const float* __restrict__ data,
                            const float* __restrict__ attnO,
                            const float* __restrict__ aout_T, const float* __restrict__ aout_b,
                            const float* __restrict__ ln1_g, const float* __restrict__ ln1_b,
                            const float* __restrict__ ff1_T, const float* __restrict__ ff1_b,
                            const float* __restrict__ ff2_T, const float* __restrict__ ff2_b,
                            const float* __restrict__ ln2_g, const float* __restrict__ ln2_b,
                            const float* __restrict__ op1_T, const float* __restrict__ b_op1,
                            float* __restrict__ val) {
    int bn = blockIdx.x;
    __shared__ float orow[C_], x1s[C_], hbuf[C_], x2s[C_];
    int c = threadIdx.x;
    float d0 = data[bn * C_ + c];
    orow[c] = attnO[bn * C_ + c];
    __syncthreads();
    float acc = aout_b[c];
    for (int j = 0; j < C_; ++j) acc = fmaf(orow[j], aout_T[j * C_ + c], acc);
    float r = d0 + acc;
    float mean = wave_sum64(r) * (1.f / 64.f);
    float df = r - mean;
    float var = wave_sum64(df * df) * (1.f / 64.f);
    float x1 = df * rsqrtf(var + 1e-5f) * ln1_g[c] + ln1_b[c];
    x1s[c] = x1;
    __syncthreads();
    acc = ff1_b[c];
    for (int j = 0; j < C_; ++j) acc = fmaf(x1s[j], ff1_T[j * C_ + c], acc);
    float ge = 0.5f * acc * (1.f + erff(acc * 0.7071067811865475f));
    hbuf[c] = ge;
    __syncthreads();
    acc = ff2_b[c];
    for (int j = 0; j < C_; ++j) acc = fmaf(hbuf[j], ff2_T[j * C_ + c], acc);
    float r2 = x1 + acc;
    float mean2 = wave_sum64(r2) * (1.f / 64.f);
    float df2 = r2 - mean2;
    float var2 = wave_sum64(df2 * df2) * (1.f / 64.f);
    float x2 = df2 * rsqrtf(var2 + 1e-5f) * ln2_g[c] + ln2_b[c];
    x2s[c] = x2;
    __syncthreads();
    #pragma unroll
    for (int rep = 0; rep < 2; ++rep) {
        int k = c + rep * 64;
        float a2 = b_op1[k];
        for (int j = 0; j < C_; ++j) a2 = fmaf(x2s[j], op1_T[j * H_ + k], a2);
        val[(size_t)bn * H_ + k] = a2;
    }
}

// ---------------- h0 = conv1d over n (96 -> 1)
__global__ void k_reduce_h0(const float* __restrict__ val,
                            const float* __restrict__ W_op2, const float* __restrict__ b_op2,
                            float* __restrict__ h0) {
    int b = blockIdx.x;
    int h = threadIdx.x;
    float acc = b_op2[0];
    for (int n = 0; n < N2T; ++n)
        acc = fmaf(val[((size_t)b * N2T + n) * H_ + h], W_op2[n], acc);
    h0[b * H_ + h] = acc;
}

// ---------------- per-step mask denominator
__global__ void k_den(const float* __restrict__ mask, float* __restrict__ den) {
    int t = blockIdx.x;
    int tid = threadIdx.x;
    float s = 0.f;
    const int total = B_ * D_;
    for (int i = tid; i < total; i += 256) {
        int b = i / D_;
        int d = i - b * D_;
        s += mask[(b * T_ + t) * D_ + d];
    }
    s = wave_sum64(s);
    __shared__ float red[4];
    if ((tid & 63) == 0) red[tid >> 6] = s;
    __syncthreads();
    if (tid == 0) den[t] = red[0] + red[1] + red[2] + red[3];
}

// ---------------- recurrent scan: 64 blocks x 512 threads, 4 batch elems/block.
// Thread-per-row f32 weight streaming from d_in (proven L2/L1-resident pattern);
// each weight row fetched once per block-step and reused across 4 batches.
// Wave <-> batch mapping: tids [bi*128, bi*128+128) = batch bi (2 waves each),
// so LDS activation reads are wave-uniform broadcasts.
__global__ __launch_bounds__(512)
void k_scan(const float* __restrict__ x, const float* __restrict__ mask,
            const float* __restrict__ deltas,
            const float* __restrict__ W_dh, const float* __restrict__ b_dh,
            const float* __restrict__ W_dx, const float* __restrict__ b_dx,
            const float* __restrict__ W_hist, const float* __restrict__ b_hist,
            const float* __restrict__ W_feat, const float* __restrict__ b_feat,
            const float* __restrict__ W_wc, const float* __restrict__ b_wc,
            const float* __restrict__ W_ih, const float* __restrict__ W_hh,
            const float* __restrict__ b_ih, const float* __restrict__ b_hh,
            const float* __restrict__ W_cls, const float* __restrict__ b_cls,
            const float* __restrict__ h0,
            float* __restrict__ out, float* __restrict__ num_part) {
    int blk = blockIdx.x;
    int b0 = blk * NB;
    int tid = threadIdx.x;
    int bi = tid >> 7;      // 0..3 batch slot
    int k  = tid & 127;     // 0..127 output index within phase

    __shared__ __align__(16) float h_s[NB][H_];
    __shared__ __align__(16) float catg_s[NB][178];  // [ximp(89) | mt(89)]
    __shared__ float xt_s[NB][D_], dt_s[NB][D_];
    __shared__ float xh_s[NB][D_], xr_s[NB][D_];
    __shared__ float catb_s[NB][178];                // [gx(89) | mt(89)]
    __shared__ float gi_s[NB][384], gh_s[NB][384];
    __shared__ float diff_s[NB][96];
    __shared__ float pl_s[NB];

    h_s[bi][k] = h0[(b0 + bi) * H_ + k];
    if (k >= D_ && k < 96) diff_s[bi][k] = 0.f;

    for (int t = 0; t < T_; ++t) {
        int base = ((b0 + bi) * T_ + t) * D_;
        if (k < D_) {
            xt_s[bi][k] = x[base + k];
            float m = mask[base + k];
            catg_s[bi][D_ + k] = m;
            catb_s[bi][D_ + k] = m;
            dt_s[bi][k] = deltas[base + k];
        }
        __syncthreads();
        // phase 1: gamma_h, decay h.  512 outputs (bi,k).
        {
            const float* wr = W_dh + k * D_;
            const float* d = dt_s[bi];
            float a0 = 0.f, a1 = 0.f;
            for (int j = 0; j < 88; j += 2) {
                a0 = fmaf(d[j],     wr[j],     a0);
                a1 = fmaf(d[j + 1], wr[j + 1], a1);
            }
            a0 = fmaf(d[88], wr[88], a0);
            float acc = b_dh[k] + a0 + a1;
            h_s[bi][k] *= __expf(-fmaxf(acc, 0.f));
        }
        __syncthreads();
        // phase 2: x_h, x_r, gamma_x.  active k<89.
        if (k < D_) {
            const float4* wr = (const float4*)(W_hist + k * H_);
            const float4* hv = (const float4*)h_s[bi];
            float a0 = 0.f, a1 = 0.f, a2 = 0.f, a3 = 0.f;
            for (int j = 0; j < 32; ++j) {
                float4 w = wr[j], hh = hv[j];
                a0 = fmaf(hh.x, w.x, a0);
                a1 = fmaf(hh.y, w.y, a1);
                a2 = fmaf(hh.z, w.z, a2);
                a3 = fmaf(hh.w, w.w, a3);
            }
            float acc = b_hist[k] + ((a0 + a1) + (a2 + a3));
            xh_s[bi][k] = acc;
            float m = catg_s[bi][D_ + k];
            xr_s[bi][k] = m * xt_s[bi][k] + (1.f - m) * acc;
            catb_s[bi][k] = __expf(-fmaxf(dt_s[bi][k] * W_dx[k * 90] + b_dx[k], 0.f));
        }
        __syncthreads();
        // phase 3: xu (off-diag), beta, x_comb, x_imp.  active k<89.
        if (k < D_) {
            const float* wf = W_feat + k * D_;
            const float* xr = xr_s[bi];
            float a0 = 0.f, a1 = 0.f;
            for (int j = 0; j < 88; j += 2) {
                a0 = fmaf(xr[j],     wf[j],     a0);
                a1 = fmaf(xr[j + 1], wf[j + 1], a1);
            }
            a0 = fmaf(xr[88], wf[88], a0);
            float xu = b_feat[k] + a0 + a1 - xr[k] * wf[k];   // remove diagonal
            const float2* wc = (const float2*)(W_wc + k * 178);
            const float2* cb = (const float2*)catb_s[bi];
            float c0 = 0.f, c1 = 0.f;
            for (int j = 0; j < 89; ++j) {
                float2 w = wc[j], v = cb[j];
                c0 = fmaf(v.x, w.x, c0);
                c1 = fmaf(v.y, w.y, c1);
            }
            float beta = b_wc[k] + c0 + c1;
            float xc = beta * xu + (1.f - beta) * xh_s[bi][k];
            float m = catg_s[bi][D_ + k];
            float xt = xt_s[bi][k];
            float xi = m * xt + (1.f - m) * xc;
            catg_s[bi][k] = xi;
            out[XIMP_OFF + base + k] = xi;
            diff_s[bi][k] = fabsf(xt - xc) * m;
        }
        __syncthreads();
        // loss partial: 4 waves, one per batch slot
        if (tid < 256) {
            int w = tid >> 6, ln = tid & 63;
            float s = diff_s[w][ln];
            if (ln < 32) s += diff_s[w][64 + ln];
            s = wave_sum64(s);
            if (ln == 0) pl_s[w] = s;
        }
        // phase 4: gi (178-dot) and gh (128-dot) for all 4 batches.  active tid<384.
        if (tid < 384) {
            const float2* wi = (const float2*)(W_ih + (size_t)tid * 178);
            const float2* cg0 = (const float2*)catg_s[0];
            const float2* cg1 = (const float2*)catg_s[1];
            const float2* cg2 = (const float2*)catg_s[2];
            const float2* cg3 = (const float2*)catg_s[3];
            float g0 = 0.f, g1 = 0.f, g2 = 0.f, g3 = 0.f;
            for (int j = 0; j < 89; ++j) {
                float2 w = wi[j];
                float2 v0 = cg0[j], v1 = cg1[j], v2 = cg2[j], v3 = cg3[j];
                g0 = fmaf(v0.x, w.x, g0); g0 = fmaf(v0.y, w.y, g0);
                g1 = fmaf(v1.x, w.x, g1); g1 = fmaf(v1.y, w.y, g1);
                g2 = fmaf(v2.x, w.x, g2); g2 = fmaf(v2.y, w.y, g2);
                g3 = fmaf(v3.x, w.x, g3); g3 = fmaf(v3.y, w.y, g3);
            }
            float bb = b_ih[tid];
            gi_s[0][tid] = bb + g0;
            gi_s[1][tid] = bb + g1;
            gi_s[2][tid] = bb + g2;
            gi_s[3][tid] = bb + g3;
            const float4* wh = (const float4*)(W_hh + (size_t)tid * H_);
            const float4* h0v = (const float4*)h_s[0];
            const float4* h1v = (const float4*)h_s[1];
            const float4* h2v = (const float4*)h_s[2];
            const float4* h3v = (const float4*)h_s[3];
            float e0 = 0.f, e1 = 0.f, e2 = 0.f, e3 = 0.f;
            for (int j = 0; j < 32; ++j) {
                float4 w = wh[j];
                float4 a = h0v[j], b = h1v[j], c = h2v[j], d = h3v[j];
                e0 = fmaf(a.x, w.x, e0); e0 = fmaf(a.y, w.y, e0); e0 = fmaf(a.z, w.z, e0); e0 = fmaf(a.w, w.w, e0);
                e1 = fmaf(b.x, w.x, e1); e1 = fmaf(b.y, w.y, e1); e1 = fmaf(b.z, w.z, e1); e1 = fmaf(b.w, w.w, e1);
                e2 = fmaf(c.x, w.x, e2); e2 = fmaf(c.y, w.y, e2); e2 = fmaf(c.z, w.z, e2); e2 = fmaf(c.w, w.w, e2);
                e3 = fmaf(d.x, w.x, e3); e3 = fmaf(d.y, w.y, e3); e3 = fmaf(d.w, w.w, e3); e3 = fmaf(d.z, w.z, e3);
            }
            float bh = b_hh[tid];
            gh_s[0][tid] = bh + e0;
            gh_s[1][tid] = bh + e1;
            gh_s[2][tid] = bh + e2;
            gh_s[3][tid] = bh + e3;
        }
        if (tid == 0) num_part[t * NBLK + blk] = pl_s[0] + pl_s[1] + pl_s[2] + pl_s[3];
        __syncthreads();
        // phase 5: GRU update.  512 outputs (bi,k).
        {
            float r = 1.f / (1.f + __expf(-(gi_s[bi][k] + gh_s[bi][k])));
            float z = 1.f / (1.f + __expf(-(gi_s[bi][H_ + k] + gh_s[bi][H_ + k])));
            float g = tanhf(gi_s[bi][2 * H_ + k] + r * gh_s[bi][2 * H_ + k]);
            float hn = (1.f - z) * g + z * h_s[bi][k];
            h_s[bi][k] = hn;
            out[HID_OFF + (size_t)((b0 + bi) * T_ + t) * H_ + k] = hn;
        }
        __syncthreads();
    }
    // classifier: per batch slot, 2 waves each -> reduce within first wave of pair
    if (tid < 256) {
        int w = tid >> 6, ln = tid & 63;
        float p = h_s[w][ln] * W_cls[ln] + h_s[w][ln + 64] * W_cls[ln + 64];
        p = wave_sum64(p);
        if (ln == 0) {
            float y = p + b_cls[0];
            out[Y_OFF + b0 + w] = y;
            out[YS_OFF + b0 + w] = 1.f / (1.f + __expf(-y));
        }
    }
}

// ---------------- final loss reduction
__global__ void k_loss(const float* __restrict__ num_part, const float* __restrict__ den,
                       float* __restrict__ out) {
    int tid = threadIdx.x;
    float v = 0.f;
    if (tid < T_) {
        float s = 0.f;
        const float* np_ = num_part + tid * NBLK;
        for (int b = 0; b < NBLK; ++b) s += np_[b];
        v = s / (den[tid] + 1e-5f);
    }
    v = wave_sum64(v);
    if (tid == 0) out[LOSS_OFF] = v;
}

extern "C" void kernel_launch(void* const* d_in, const int* in_sizes, int n_in,
                              void* d_out, int out_size, void* d_ws, size_t ws_size,
                              hipStream_t stream) {
    const float* x        = (const float*)d_in[0];
    const float* mask     = (const float*)d_in[1];
    const float* deltas   = (const float*)d_in[2];
    const float* last_obs = (const float*)d_in[3];
    const float* medians  = (const float*)d_in[4];
    const float* W_dh  = (const float*)d_in[5];
    const float* b_dh  = (const float*)d_in[6];
    const float* W_dx  = (const float*)d_in[7];
    const float* b_dx  = (const float*)d_in[8];
    const float* W_hist= (const float*)d_in[9];
    const float* b_hist= (const float*)d_in[10];
    const float* W_feat= (const float*)d_in[11];
    const float* b_feat= (const float*)d_in[12];
    const float* W_wc  = (const float*)d_in[13];
    const float* b_wc  = (const float*)d_in[14];
    const float* W_wo  = (const float*)d_in[15];
    const float* b_wo  = (const float*)d_in[16];
    const float* W_cls = (const float*)d_in[17];
    const float* b_cls = (const float*)d_in[18];
    const float* W_ih  = (const float*)d_in[19];
    const float* W_hh  = (const float*)d_in[20];
    const float* b_ih  = (const float*)d_in[21];
    const float* b_hh  = (const float*)d_in[22];
    const float* W_inp = (const float*)d_in[23];
    const float* b_inp = (const float*)d_in[24];
    const float* W_op1 = (const float*)d_in[25];
    const float* b_op1 = (const float*)d_in[26];
    const float* W_op2 = (const float*)d_in[27];
    const float* b_op2 = (const float*)d_in[28];
    const float* attn_in_w  = (const float*)d_in[29];
    const float* attn_in_b  = (const float*)d_in[30];
    const float* attn_out_w = (const float*)d_in[31];
    const float* attn_out_b = (const float*)d_in[32];
    const float* ln1_g = (const float*)d_in[33];
    const float* ln1_b = (const float*)d_in[34];
    const float* ln2_g = (const float*)d_in[35];
    const float* ln2_b = (const float*)d_in[36];
    const float* ff1_w = (const float*)d_in[37];
    const float* ff1_b = (const float*)d_in[38];
    const float* ff2_w = (const float*)d_in[39];
    const float* ff2_b = (const float*)d_in[40];

    float* out = (float*)d_out;
    float* ws = (float*)d_ws;

    float* data  = ws;                                  // B*96*64
    float* qb    = data  + (size_t)B_ * N2T * C_;
    float* kb    = qb    + (size_t)N2T * NH_ * B_ * HD_;
    float* vb    = kb    + (size_t)N2T * NH_ * B_ * HD_;
    float* attnO = vb    + (size_t)N2T * NH_ * B_ * HD_;
    float* val   = attnO + (size_t)B_ * N2T * C_;       // B*96*128
    float* h0    = val   + (size_t)B_ * N2T * H_;
    float* den   = h0    + (size_t)B_ * H_;
    float* nump  = den   + 64;                          // 48*64
    float* W_woT = nump  + T_ * NBLK;
    float* W_inpT= W_woT + 7921;
    float* ain_T = W_inpT + 5696;
    float* aout_T= ain_T + 12288;
    float* ff1_T = aout_T + 4096;
    float* ff2_T = ff1_T + 4096;
    float* op1_T = ff2_T + 4096;

    k_prep<<<182, 256, 0, stream>>>(W_wo, W_inp, attn_in_w, attn_out_w, ff1_w, ff2_w, W_op1,
                                    W_woT, W_inpT, ain_T, aout_T, ff1_T, ff2_T, op1_T);
    k_phaseA<<<B_ * T_, 128, 0, stream>>>(last_obs, deltas, medians, W_woT, b_wo, W_inpT, b_inp, data);
    k_qkv<<<B_ * N2T, 192, 0, stream>>>(data, ain_T, attn_in_b, qb, kb, vb);
    k_attn<<<N2T * NH_, 256, 0, stream>>>(qb, kb, vb, attnO);
    k_transform<<<B_ * N2T, 64, 0, stream>>>(data, attnO, aout_T, attn_out_b,
                                             ln1_g, ln1_b, ff1_T, ff1_b, ff2_T, ff2_b,
                                             ln2_g, ln2_b, op1_T, b_op1, val);
    k_reduce_h0<<<B_, H_, 0, stream>>>(val, W_op2, b_op2, h0);
    k_den<<<T_, 256, 0, stream>>>(mask, den);
    k_scan<<<NBLK, 512, 0, stream>>>(x, mask, deltas,
                                     W_dh, b_dh, W_dx, b_dx, W_hist, b_hist, W_feat, b_feat,
                                     W_wc, b_wc, W_ih, W_hh, b_ih, b_hh, W_cls, b_cls,
                                     h0, out, nump);
    k_loss<<<1, 64, 0, stream>>>(nump, den, out);
}